// Round 1
// baseline (88.518 us; speedup 1.0000x reference)
//
#include <hip/hip_runtime.h>
#include <math.h>

#define BATCH  16
#define NSETS  128
#define NGENES 20000

__device__ __forceinline__ float sigmoid_f(float x) {
    return 1.0f / (1.0f + expf(-x));
}

// -------- kernel 1: per-set mean of sigmoid(set_membership) --------
__global__ void avg_kernel(const float* __restrict__ sm, float* __restrict__ avg) {
    int k = blockIdx.x;
    const float* row = sm + (size_t)k * NGENES;
    float s = 0.0f;
    for (int j = threadIdx.x; j < NGENES; j += blockDim.x)
        s += sigmoid_f(row[j]);
    // wave reduce (64 lanes)
    for (int off = 32; off > 0; off >>= 1) s += __shfl_down(s, off, 64);
    __shared__ float red[8];
    int wid = threadIdx.x >> 6, lid = threadIdx.x & 63;
    if (lid == 0) red[wid] = s;
    __syncthreads();
    if (threadIdx.x == 0) {
        float t = 0.0f;
        int nw = blockDim.x >> 6;
        for (int i = 0; i < nw; i++) t += red[i];
        avg[k] = t / (float)NGENES;
    }
}

// -------- kernel 2: down-weighted indicators --------
__global__ void ind_kernel(const float* __restrict__ sm, const float* __restrict__ avg,
                           float* __restrict__ indDW) {
    int k = blockIdx.y;
    int j = blockIdx.x * blockDim.x + threadIdx.x;
    if (j >= NGENES) return;
    float ind = sigmoid_f(sm[(size_t)k * NGENES + j]);
    float thr = avg[k] * 0.3f;
    if (ind < thr) ind *= 0.01f;
    indDW[(size_t)k * NGENES + j] = ind;
}

// -------- kernel 3: invert permutation into rank weights --------
// wgt[b, S[b,g]] = (float)(NGENES - g)
__global__ void wgt_kernel(const int* __restrict__ S, float* __restrict__ wgt) {
    int b = blockIdx.y;
    int g = blockIdx.x * blockDim.x + threadIdx.x;
    if (g >= NGENES) return;
    int j = S[(size_t)b * NGENES + g];
    wgt[(size_t)b * NGENES + j] = (float)(NGENES - g);
}

// -------- kernel 4: main reduction, one block per (b,k) --------
__device__ __forceinline__ void accum(float ind, float r, float wg,
                                      float& s_pos, float& c_pos,
                                      float& s_neg, float& c_neg) {
    float x = fminf(fmaxf(r * ind, 1e-8f), 10000.0f);
    float w = sqrtf(sqrtf(x));        // x^0.25
    s_pos += w;
    c_pos = fmaf(w, wg, c_pos);
    float n = (ind < 0.1f) ? 1.0f : 0.0f;
    s_neg += n;
    c_neg = fmaf(n, wg, c_neg);
}

__global__ __launch_bounds__(256, 8)
void main_kernel(const float* __restrict__ R, const float* __restrict__ indDW,
                 const float* __restrict__ wgt, float* __restrict__ out) {
    int blk = blockIdx.x;
    int k = blk & (NSETS - 1);
    int b = blk >> 7;
    const float4* __restrict__ iv = (const float4*)(indDW + (size_t)k * NGENES);
    const float4* __restrict__ rv = (const float4*)(R + (size_t)b * NGENES);
    const float4* __restrict__ wv = (const float4*)(wgt + (size_t)b * NGENES);

    float s_pos = 0.0f, c_pos = 0.0f, s_neg = 0.0f, c_neg = 0.0f;
    const int NV = NGENES / 4;   // 5000, NGENES % 4 == 0
    for (int v = threadIdx.x; v < NV; v += blockDim.x) {
        float4 i4 = iv[v];
        float4 r4 = rv[v];
        float4 w4 = wv[v];
        accum(i4.x, r4.x, w4.x, s_pos, c_pos, s_neg, c_neg);
        accum(i4.y, r4.y, w4.y, s_pos, c_pos, s_neg, c_neg);
        accum(i4.z, r4.z, w4.z, s_pos, c_pos, s_neg, c_neg);
        accum(i4.w, r4.w, w4.w, s_pos, c_pos, s_neg, c_neg);
    }

    // wave reduce all four
    for (int off = 32; off > 0; off >>= 1) {
        s_pos += __shfl_down(s_pos, off, 64);
        c_pos += __shfl_down(c_pos, off, 64);
        s_neg += __shfl_down(s_neg, off, 64);
        c_neg += __shfl_down(c_neg, off, 64);
    }
    __shared__ float red[4][4];
    int wid = threadIdx.x >> 6, lid = threadIdx.x & 63;
    if (lid == 0) {
        red[wid][0] = s_pos; red[wid][1] = c_pos;
        red[wid][2] = s_neg; red[wid][3] = c_neg;
    }
    __syncthreads();
    if (threadIdx.x == 0) {
        float sp = 0, cp = 0, sn = 0, cn = 0;
        for (int i = 0; i < 4; i++) {
            sp += red[i][0]; cp += red[i][1];
            sn += red[i][2]; cn += red[i][3];
        }
        float ep = (sp > 1e-8f) ? cp / (sp + 1e-10f) : 0.0f;
        float en = (sn > 1e-8f) ? cn / (sn + 1e-10f) : 0.0f;
        out[blk] = (ep - en) / (float)NGENES;   // blk == b*NSETS + k
    }
}

// -------- fallback (ws too small): self-contained gather version --------
__global__ void fallback_kernel(const float* __restrict__ R, const float* __restrict__ sm,
                                const int* __restrict__ S, float* __restrict__ out) {
    int blk = blockIdx.x;
    int k = blk & (NSETS - 1);
    int b = blk >> 7;
    const float* smrow = sm + (size_t)k * NGENES;

    // per-block avg of sigmoid
    float s = 0.0f;
    for (int j = threadIdx.x; j < NGENES; j += blockDim.x)
        s += sigmoid_f(smrow[j]);
    for (int off = 32; off > 0; off >>= 1) s += __shfl_down(s, off, 64);
    __shared__ float red[4][4];
    __shared__ float avg_sh;
    int wid = threadIdx.x >> 6, lid = threadIdx.x & 63;
    if (lid == 0) red[wid][0] = s;
    __syncthreads();
    if (threadIdx.x == 0) {
        float t = 0.0f;
        for (int i = 0; i < 4; i++) t += red[i][0];
        avg_sh = t / (float)NGENES;
    }
    __syncthreads();
    float thr = avg_sh * 0.3f;

    float s_pos = 0.0f, c_pos = 0.0f, s_neg = 0.0f, c_neg = 0.0f;
    for (int g = threadIdx.x; g < NGENES; g += blockDim.x) {
        int j = S[(size_t)b * NGENES + g];
        float ind = sigmoid_f(smrow[j]);
        if (ind < thr) ind *= 0.01f;
        float r = R[(size_t)b * NGENES + j];
        float wg = (float)(NGENES - g);
        accum(ind, r, wg, s_pos, c_pos, s_neg, c_neg);
    }
    for (int off = 32; off > 0; off >>= 1) {
        s_pos += __shfl_down(s_pos, off, 64);
        c_pos += __shfl_down(c_pos, off, 64);
        s_neg += __shfl_down(s_neg, off, 64);
        c_neg += __shfl_down(c_neg, off, 64);
    }
    __syncthreads();
    if (lid == 0) {
        red[wid][0] = s_pos; red[wid][1] = c_pos;
        red[wid][2] = s_neg; red[wid][3] = c_neg;
    }
    __syncthreads();
    if (threadIdx.x == 0) {
        float sp = 0, cp = 0, sn = 0, cn = 0;
        for (int i = 0; i < 4; i++) {
            sp += red[i][0]; cp += red[i][1];
            sn += red[i][2]; cn += red[i][3];
        }
        float ep = (sp > 1e-8f) ? cp / (sp + 1e-10f) : 0.0f;
        float en = (sn > 1e-8f) ? cn / (sn + 1e-10f) : 0.0f;
        out[blk] = (ep - en) / (float)NGENES;
    }
}

extern "C" void kernel_launch(void* const* d_in, const int* in_sizes, int n_in,
                              void* d_out, int out_size, void* d_ws, size_t ws_size,
                              hipStream_t stream) {
    const float* R  = (const float*)d_in[0];
    const float* sm = (const float*)d_in[1];
    const int*   S  = (const int*)d_in[2];
    float* out = (float*)d_out;

    size_t need = (size_t)NSETS * 4                      // avg
                + (size_t)NSETS * NGENES * 4             // indDW
                + (size_t)BATCH * NGENES * 4;            // wgt

    if (ws_size >= need) {
        float* avg   = (float*)d_ws;
        float* indDW = avg + NSETS;                      // offset 512 B (16-aligned)
        float* wgt   = indDW + (size_t)NSETS * NGENES;   // 80000-B rows (16-aligned)

        avg_kernel<<<NSETS, 256, 0, stream>>>(sm, avg);
        dim3 gi((NGENES + 255) / 256, NSETS);
        ind_kernel<<<gi, 256, 0, stream>>>(sm, avg, indDW);
        dim3 gw((NGENES + 255) / 256, BATCH);
        wgt_kernel<<<gw, 256, 0, stream>>>(S, wgt);
        main_kernel<<<BATCH * NSETS, 256, 0, stream>>>(R, indDW, wgt, out);
    } else {
        fallback_kernel<<<BATCH * NSETS, 256, 0, stream>>>(R, sm, S, out);
    }
}

// Round 2
// 45.255 us; speedup vs baseline: 1.9560x; 1.9560x over previous
//
#include <hip/hip_runtime.h>
#include <math.h>

#define BATCH  16
#define NSETS  128
#define NGENES 20000
#define KPB    8      // sets per block in main kernel
#define TPBM   512    // threads per block in main kernel

__device__ __forceinline__ float sigmoid_f(float x) {
    return 1.0f / (1.0f + expf(-x));   // precise: preserves threshold-flip behavior
}

// -------- kernel 1 (fused): sigmoid -> avg -> downweight -> store + neg count --------
__global__ __launch_bounds__(1024)
void ind_fused_kernel(const float* __restrict__ sm,
                      float* __restrict__ indDW, float* __restrict__ sneg) {
    int k = blockIdx.x;
    const float* row = sm + (size_t)k * NGENES;
    float* orow = indDW + (size_t)k * NGENES;

    // pass 1: mean of sigmoid
    float s = 0.0f;
    for (int j = threadIdx.x; j < NGENES; j += 1024)
        s += sigmoid_f(row[j]);
    for (int off = 32; off > 0; off >>= 1) s += __shfl_down(s, off, 64);
    __shared__ float red[16];
    __shared__ float avg_sh;
    int wid = threadIdx.x >> 6, lid = threadIdx.x & 63;
    if (lid == 0) red[wid] = s;
    __syncthreads();
    if (threadIdx.x == 0) {
        float t = 0.0f;
        for (int i = 0; i < 16; i++) t += red[i];
        avg_sh = t / (float)NGENES;
    }
    __syncthreads();
    float thr = avg_sh * 0.3f;

    // pass 2: recompute sigmoid, downweight, store, count neg flags
    float cnt = 0.0f;
    for (int j = threadIdx.x; j < NGENES; j += 1024) {
        float v = sigmoid_f(row[j]);
        if (v < thr) v *= 0.01f;
        orow[j] = v;
        cnt += (v < 0.1f) ? 1.0f : 0.0f;
    }
    for (int off = 32; off > 0; off >>= 1) cnt += __shfl_down(cnt, off, 64);
    __syncthreads();                       // red[] reuse
    if (lid == 0) red[wid] = cnt;
    __syncthreads();
    if (threadIdx.x == 0) {
        float t = 0.0f;
        for (int i = 0; i < 16; i++) t += red[i];
        sneg[k] = t;
    }
}

// -------- kernel 2: invert permutation into rank weights --------
// wgt[b, S[b,g]] = (float)(NGENES - g)
__global__ void wgt_kernel(const int* __restrict__ S, float* __restrict__ wgt) {
    int b = blockIdx.y;
    int g = blockIdx.x * blockDim.x + threadIdx.x;
    if (g >= NGENES) return;
    int j = S[(size_t)b * NGENES + g];
    wgt[(size_t)b * NGENES + j] = (float)(NGENES - g);
}

// -------- kernel 3: main reduction, one block per (b, 8-set group) --------
__device__ __forceinline__ void accum(float ind, float r, float wg,
                                      float& s_pos, float& c_pos, float& c_neg) {
    // r < 1 and ind < 1 so the upper clamp (10000) never binds
    float x = fmaxf(r * ind, 1e-8f);
    float w = __builtin_amdgcn_sqrtf(__builtin_amdgcn_sqrtf(x));   // x^0.25, ~2 ULP
    s_pos += w;
    c_pos = fmaf(w, wg, c_pos);
    c_neg += (ind < 0.1f) ? wg : 0.0f;
}

__global__ __launch_bounds__(TPBM, 2)
void main_kernel(const float* __restrict__ R, const float* __restrict__ indDW,
                 const float* __restrict__ wgt, const float* __restrict__ sneg,
                 float* __restrict__ out) {
    int blk = blockIdx.x;                 // b * (NSETS/KPB) + kg
    int kg = blk & (NSETS / KPB - 1);     // 0..15
    int b  = blk / (NSETS / KPB);
    int k0 = kg * KPB;
    const float4* __restrict__ rv = (const float4*)(R   + (size_t)b * NGENES);
    const float4* __restrict__ wv = (const float4*)(wgt + (size_t)b * NGENES);

    float s_pos[KPB], c_pos[KPB], c_neg[KPB];
    #pragma unroll
    for (int kk = 0; kk < KPB; kk++) { s_pos[kk] = 0.f; c_pos[kk] = 0.f; c_neg[kk] = 0.f; }

    const int NV = NGENES / 4;            // 5000
    for (int v = threadIdx.x; v < NV; v += TPBM) {
        float4 r4 = rv[v];
        float4 w4 = wv[v];
        #pragma unroll
        for (int kk = 0; kk < KPB; kk++) {
            const float4 i4 = ((const float4*)(indDW + (size_t)(k0 + kk) * NGENES))[v];
            accum(i4.x, r4.x, w4.x, s_pos[kk], c_pos[kk], c_neg[kk]);
            accum(i4.y, r4.y, w4.y, s_pos[kk], c_pos[kk], c_neg[kk]);
            accum(i4.z, r4.z, w4.z, s_pos[kk], c_pos[kk], c_neg[kk]);
            accum(i4.w, r4.w, w4.w, s_pos[kk], c_pos[kk], c_neg[kk]);
        }
    }

    // reduce: wave-level shuffles, then LDS across the 8 waves
    #pragma unroll
    for (int kk = 0; kk < KPB; kk++) {
        for (int off = 32; off > 0; off >>= 1) {
            s_pos[kk] += __shfl_down(s_pos[kk], off, 64);
            c_pos[kk] += __shfl_down(c_pos[kk], off, 64);
            c_neg[kk] += __shfl_down(c_neg[kk], off, 64);
        }
    }
    __shared__ float red[TPBM / 64][KPB][3];
    int wid = threadIdx.x >> 6, lid = threadIdx.x & 63;
    if (lid == 0) {
        #pragma unroll
        for (int kk = 0; kk < KPB; kk++) {
            red[wid][kk][0] = s_pos[kk];
            red[wid][kk][1] = c_pos[kk];
            red[wid][kk][2] = c_neg[kk];
        }
    }
    __syncthreads();
    if (threadIdx.x < KPB) {
        int kk = threadIdx.x;
        float sp = 0.f, cp = 0.f, cn = 0.f;
        for (int w = 0; w < TPBM / 64; w++) {
            sp += red[w][kk][0];
            cp += red[w][kk][1];
            cn += red[w][kk][2];
        }
        float sn = sneg[k0 + kk];
        float ep = (sp > 1e-8f) ? cp / (sp + 1e-10f) : 0.0f;
        float en = (sn > 1e-8f) ? cn / (sn + 1e-10f) : 0.0f;
        out[(size_t)b * NSETS + k0 + kk] = (ep - en) / (float)NGENES;
    }
}

// -------- fallback (ws too small): self-contained gather version --------
__global__ void fallback_kernel(const float* __restrict__ R, const float* __restrict__ sm,
                                const int* __restrict__ S, float* __restrict__ out) {
    int blk = blockIdx.x;
    int k = blk & (NSETS - 1);
    int b = blk >> 7;
    const float* smrow = sm + (size_t)k * NGENES;

    float s = 0.0f;
    for (int j = threadIdx.x; j < NGENES; j += blockDim.x)
        s += sigmoid_f(smrow[j]);
    for (int off = 32; off > 0; off >>= 1) s += __shfl_down(s, off, 64);
    __shared__ float red[4][4];
    __shared__ float avg_sh;
    int wid = threadIdx.x >> 6, lid = threadIdx.x & 63;
    if (lid == 0) red[wid][0] = s;
    __syncthreads();
    if (threadIdx.x == 0) {
        float t = 0.0f;
        for (int i = 0; i < 4; i++) t += red[i][0];
        avg_sh = t / (float)NGENES;
    }
    __syncthreads();
    float thr = avg_sh * 0.3f;

    float s_pos = 0.0f, c_pos = 0.0f, s_neg = 0.0f, c_neg = 0.0f;
    for (int g = threadIdx.x; g < NGENES; g += blockDim.x) {
        int j = S[(size_t)b * NGENES + g];
        float ind = sigmoid_f(smrow[j]);
        if (ind < thr) ind *= 0.01f;
        float r = R[(size_t)b * NGENES + j];
        float wg = (float)(NGENES - g);
        float x = fminf(fmaxf(r * ind, 1e-8f), 10000.0f);
        float w = sqrtf(sqrtf(x));
        s_pos += w;
        c_pos = fmaf(w, wg, c_pos);
        float n = (ind < 0.1f) ? 1.0f : 0.0f;
        s_neg += n;
        c_neg = fmaf(n, wg, c_neg);
    }
    for (int off = 32; off > 0; off >>= 1) {
        s_pos += __shfl_down(s_pos, off, 64);
        c_pos += __shfl_down(c_pos, off, 64);
        s_neg += __shfl_down(s_neg, off, 64);
        c_neg += __shfl_down(c_neg, off, 64);
    }
    __syncthreads();
    if (lid == 0) {
        red[wid][0] = s_pos; red[wid][1] = c_pos;
        red[wid][2] = s_neg; red[wid][3] = c_neg;
    }
    __syncthreads();
    if (threadIdx.x == 0) {
        float sp = 0, cp = 0, sn = 0, cn = 0;
        for (int i = 0; i < 4; i++) {
            sp += red[i][0]; cp += red[i][1];
            sn += red[i][2]; cn += red[i][3];
        }
        float ep = (sp > 1e-8f) ? cp / (sp + 1e-10f) : 0.0f;
        float en = (sn > 1e-8f) ? cn / (sn + 1e-10f) : 0.0f;
        out[blk] = (ep - en) / (float)NGENES;
    }
}

extern "C" void kernel_launch(void* const* d_in, const int* in_sizes, int n_in,
                              void* d_out, int out_size, void* d_ws, size_t ws_size,
                              hipStream_t stream) {
    const float* R  = (const float*)d_in[0];
    const float* sm = (const float*)d_in[1];
    const int*   S  = (const int*)d_in[2];
    float* out = (float*)d_out;

    size_t need = ((size_t)NSETS * NGENES      // indDW
                 + (size_t)BATCH * NGENES      // wgt
                 + NSETS) * 4;                 // sneg

    if (ws_size >= need) {
        float* indDW = (float*)d_ws;
        float* wgt   = indDW + (size_t)NSETS * NGENES;
        float* sneg  = wgt + (size_t)BATCH * NGENES;

        ind_fused_kernel<<<NSETS, 1024, 0, stream>>>(sm, indDW, sneg);
        dim3 gw((NGENES + 255) / 256, BATCH);
        wgt_kernel<<<gw, 256, 0, stream>>>(S, wgt);
        main_kernel<<<BATCH * (NSETS / KPB), TPBM, 0, stream>>>(R, indDW, wgt, sneg, out);
    } else {
        fallback_kernel<<<BATCH * NSETS, 256, 0, stream>>>(R, sm, S, out);
    }
}

// Round 3
// 41.635 us; speedup vs baseline: 2.1261x; 1.0869x over previous
//
#include <hip/hip_runtime.h>
#include <math.h>

#define BATCH  16
#define NSETS  128
#define NGENES 20000
#define KPB    8      // sets per block in main kernel
#define TPBM   1024   // threads per block in main kernel
#define NEG_T  0.1f

__device__ __forceinline__ float sigmoid_fast(float x) {
    // v_exp_f32-based; ~2 ulp. Flip-risk at thresholds analyzed: negligible.
    return __builtin_amdgcn_rcpf(1.0f + __expf(-x));
}

__device__ __forceinline__ float pow025(float x) {
    return __builtin_amdgcn_sqrtf(__builtin_amdgcn_sqrtf(x));
}

// -------- kernel 1: per-set avg -> downweight -> sind = (neg ? -1 : +1)*ind^0.25, sneg --------
__global__ __launch_bounds__(1024)
void ind_kernel(const float* __restrict__ sm, float* __restrict__ sind,
                float* __restrict__ sneg) {
    int k = blockIdx.x;
    const float* row = sm + (size_t)k * NGENES;
    float* orow = sind + (size_t)k * NGENES;

    // pass 1: mean of sigmoid (deterministic block reduce)
    float s = 0.0f;
    for (int j = threadIdx.x; j < NGENES; j += 1024)
        s += sigmoid_fast(row[j]);
    for (int off = 32; off > 0; off >>= 1) s += __shfl_down(s, off, 64);
    __shared__ float red[16];
    __shared__ float avg_sh;
    int wid = threadIdx.x >> 6, lid = threadIdx.x & 63;
    if (lid == 0) red[wid] = s;
    __syncthreads();
    if (threadIdx.x == 0) {
        float t = 0.0f;
        for (int i = 0; i < 16; i++) t += red[i];
        avg_sh = t / (float)NGENES;
    }
    __syncthreads();
    float thr = avg_sh * 0.3f;

    // pass 2: downweight, ^0.25, sign-encode neg flag, store; count negs
    float cnt = 0.0f;
    for (int j = threadIdx.x; j < NGENES; j += 1024) {
        float v = sigmoid_fast(row[j]);
        if (v < thr) v *= 0.01f;
        float q = pow025(v);
        bool neg = (v < NEG_T);          // exact test on downweighted value
        orow[j] = neg ? -q : q;
        cnt += neg ? 1.0f : 0.0f;
    }
    for (int off = 32; off > 0; off >>= 1) cnt += __shfl_down(cnt, off, 64);
    __syncthreads();
    if (lid == 0) red[wid] = cnt;
    __syncthreads();
    if (threadIdx.x == 0) {
        float t = 0.0f;                   // integer-valued: exact in f32
        for (int i = 0; i < 16; i++) t += red[i];
        sneg[k] = t;
    }
}

// -------- kernel 2: rank-weight scatter + r^0.25 --------
__global__ void prep_kernel(const float* __restrict__ R, const int* __restrict__ S,
                            float* __restrict__ r4, float* __restrict__ wgt) {
    int b = blockIdx.y;
    int i = blockIdx.x * blockDim.x + threadIdx.x;
    if (i >= NGENES) return;
    int j = S[(size_t)b * NGENES + i];
    wgt[(size_t)b * NGENES + j] = (float)(NGENES - i);   // S is a permutation: full coverage
    float r = R[(size_t)b * NGENES + i];
    r4[(size_t)b * NGENES + i] = pow025(r);
}

// -------- kernel 3: main reduction, zero transcendentals --------
// w = max(r*ind, 1e-8)^0.25 == max(r4*ind4, 0.01)  (monotone pow, exact)
__device__ __forceinline__ void accum(float si, float rr, float wg,
                                      float& sp, float& cp, float& cn) {
    float w = fmaxf(fabsf(si) * rr, 0.01f);   // fabs folds into mul input modifier
    sp += w;
    cp = fmaf(w, wg, cp);
    cn += (si < 0.0f) ? wg : 0.0f;
}

__global__ __launch_bounds__(TPBM)
void main_kernel(const float* __restrict__ sind, const float* __restrict__ r4,
                 const float* __restrict__ wgt, const float* __restrict__ sneg,
                 float* __restrict__ out) {
    int blk = blockIdx.x;                 // b * (NSETS/KPB) + kg ; kg%8 pins XCD
    int kg = blk & (NSETS / KPB - 1);     // 0..15
    int b  = blk / (NSETS / KPB);
    int k0 = kg * KPB;
    const float4* __restrict__ rv = (const float4*)(r4  + (size_t)b * NGENES);
    const float4* __restrict__ wv = (const float4*)(wgt + (size_t)b * NGENES);

    float sp[KPB], cp[KPB], cn[KPB];
    #pragma unroll
    for (int kk = 0; kk < KPB; kk++) { sp[kk] = 0.f; cp[kk] = 0.f; cn[kk] = 0.f; }

    const int NV = NGENES / 4;            // 5000
    for (int v = threadIdx.x; v < NV; v += TPBM) {
        float4 rr = rv[v];
        float4 ww = wv[v];
        #pragma unroll
        for (int kk = 0; kk < KPB; kk++) {
            const float4 s4 = ((const float4*)(sind + (size_t)(k0 + kk) * NGENES))[v];
            accum(s4.x, rr.x, ww.x, sp[kk], cp[kk], cn[kk]);
            accum(s4.y, rr.y, ww.y, sp[kk], cp[kk], cn[kk]);
            accum(s4.z, rr.z, ww.z, sp[kk], cp[kk], cn[kk]);
            accum(s4.w, rr.w, ww.w, sp[kk], cp[kk], cn[kk]);
        }
    }

    #pragma unroll
    for (int kk = 0; kk < KPB; kk++) {
        for (int off = 32; off > 0; off >>= 1) {
            sp[kk] += __shfl_down(sp[kk], off, 64);
            cp[kk] += __shfl_down(cp[kk], off, 64);
            cn[kk] += __shfl_down(cn[kk], off, 64);
        }
    }
    __shared__ float red[TPBM / 64][KPB][3];
    int wid = threadIdx.x >> 6, lid = threadIdx.x & 63;
    if (lid == 0) {
        #pragma unroll
        for (int kk = 0; kk < KPB; kk++) {
            red[wid][kk][0] = sp[kk];
            red[wid][kk][1] = cp[kk];
            red[wid][kk][2] = cn[kk];
        }
    }
    __syncthreads();
    if (threadIdx.x < KPB) {
        int kk = threadIdx.x;
        float tsp = 0.f, tcp = 0.f, tcn = 0.f;
        for (int w = 0; w < TPBM / 64; w++) {
            tsp += red[w][kk][0];
            tcp += red[w][kk][1];
            tcn += red[w][kk][2];
        }
        float sn = sneg[k0 + kk];
        float ep = (tsp > 1e-8f) ? tcp / (tsp + 1e-10f) : 0.0f;
        float en = (sn  > 1e-8f) ? tcn / (sn  + 1e-10f) : 0.0f;
        out[(size_t)b * NSETS + k0 + kk] = (ep - en) / (float)NGENES;
    }
}

// -------- fallback (ws too small): self-contained gather version --------
__global__ void fallback_kernel(const float* __restrict__ R, const float* __restrict__ sm,
                                const int* __restrict__ S, float* __restrict__ out) {
    int blk = blockIdx.x;
    int k = blk & (NSETS - 1);
    int b = blk >> 7;
    const float* smrow = sm + (size_t)k * NGENES;

    float s = 0.0f;
    for (int j = threadIdx.x; j < NGENES; j += blockDim.x)
        s += 1.0f / (1.0f + expf(-smrow[j]));
    for (int off = 32; off > 0; off >>= 1) s += __shfl_down(s, off, 64);
    __shared__ float red[4][4];
    __shared__ float avg_sh;
    int wid = threadIdx.x >> 6, lid = threadIdx.x & 63;
    if (lid == 0) red[wid][0] = s;
    __syncthreads();
    if (threadIdx.x == 0) {
        float t = 0.0f;
        for (int i = 0; i < 4; i++) t += red[i][0];
        avg_sh = t / (float)NGENES;
    }
    __syncthreads();
    float thr = avg_sh * 0.3f;

    float s_pos = 0.0f, c_pos = 0.0f, s_neg = 0.0f, c_neg = 0.0f;
    for (int g = threadIdx.x; g < NGENES; g += blockDim.x) {
        int j = S[(size_t)b * NGENES + g];
        float ind = 1.0f / (1.0f + expf(-smrow[j]));
        if (ind < thr) ind *= 0.01f;
        float r = R[(size_t)b * NGENES + j];
        float wg = (float)(NGENES - g);
        float x = fminf(fmaxf(r * ind, 1e-8f), 10000.0f);
        float w = sqrtf(sqrtf(x));
        s_pos += w;
        c_pos = fmaf(w, wg, c_pos);
        float n = (ind < NEG_T) ? 1.0f : 0.0f;
        s_neg += n;
        c_neg = fmaf(n, wg, c_neg);
    }
    for (int off = 32; off > 0; off >>= 1) {
        s_pos += __shfl_down(s_pos, off, 64);
        c_pos += __shfl_down(c_pos, off, 64);
        s_neg += __shfl_down(s_neg, off, 64);
        c_neg += __shfl_down(c_neg, off, 64);
    }
    __syncthreads();
    if (lid == 0) {
        red[wid][0] = s_pos; red[wid][1] = c_pos;
        red[wid][2] = s_neg; red[wid][3] = c_neg;
    }
    __syncthreads();
    if (threadIdx.x == 0) {
        float sp = 0, cp = 0, sn = 0, cn = 0;
        for (int i = 0; i < 4; i++) {
            sp += red[i][0]; cp += red[i][1];
            sn += red[i][2]; cn += red[i][3];
        }
        float ep = (sp > 1e-8f) ? cp / (sp + 1e-10f) : 0.0f;
        float en = (sn > 1e-8f) ? cn / (sn + 1e-10f) : 0.0f;
        out[blk] = (ep - en) / (float)NGENES;
    }
}

extern "C" void kernel_launch(void* const* d_in, const int* in_sizes, int n_in,
                              void* d_out, int out_size, void* d_ws, size_t ws_size,
                              hipStream_t stream) {
    const float* R  = (const float*)d_in[0];
    const float* sm = (const float*)d_in[1];
    const int*   S  = (const int*)d_in[2];
    float* out = (float*)d_out;

    size_t need = ((size_t)NSETS * NGENES        // sind
                 + 2 * (size_t)BATCH * NGENES    // r4, wgt
                 + NSETS) * 4;                   // sneg

    if (ws_size >= need) {
        float* sind = (float*)d_ws;
        float* r4v  = sind + (size_t)NSETS * NGENES;
        float* wgt  = r4v + (size_t)BATCH * NGENES;
        float* sneg = wgt + (size_t)BATCH * NGENES;

        ind_kernel<<<NSETS, 1024, 0, stream>>>(sm, sind, sneg);
        dim3 gp((NGENES + 255) / 256, BATCH);
        prep_kernel<<<gp, 256, 0, stream>>>(R, S, r4v, wgt);
        main_kernel<<<BATCH * (NSETS / KPB), TPBM, 0, stream>>>(sind, r4v, wgt, sneg, out);
    } else {
        fallback_kernel<<<BATCH * NSETS, 256, 0, stream>>>(R, sm, S, out);
    }
}